// Round 8
// baseline (2280.878 us; speedup 1.0000x reference)
//
#include <hip/hip_runtime.h>

#ifndef __has_builtin
#define __has_builtin(x) 0
#endif

__device__ __forceinline__ float fexp2(float x) {
#if __has_builtin(__builtin_amdgcn_exp2f)
    return __builtin_amdgcn_exp2f(x);   // v_exp_f32 (2^x)
#else
    return exp2f(x);
#endif
}
__device__ __forceinline__ float flog2(float x) {
#if __has_builtin(__builtin_amdgcn_logf)
    return __builtin_amdgcn_logf(x);    // v_log_f32 (log2 x)
#else
    return log2f(x);
#endif
}

#define NMAXN 128
#define DD    64
#define MAX_ITERS 500

// -1e5 * log2(e)  (NEG surrogate in log2 domain)
#define NEG2  (-144269.50408889634f)
// -(log2(e) / eps), eps = 1e-3 : logK2 = M * LKSC
#define LKSC  (-1442.6950408889634f)
// -(eps * ln2) : out = acc * OUTSC
#define OUTSC (-6.931471805599453e-4f)

struct SmemStage {
    float A[NMAXN * 33];   // set1 chunk [128][32] padded
    float B[NMAXN * 33];   // set2 chunk
    float nA[NMAXN];       // row norms set1
    float nB[NMAXN];       // row norms set2
};
struct SmemSink {
    // U-phase partials: [row*10 + w] -> (max,sum). Stride 10 float2 keeps the
    // 2-at-a-time float4 reads 16B-aligned (80B per row).
    float2 part[NMAXN * 10];
    float  u[NMAXN];
};
union SmemU {
    SmemStage st;
    SmemSink  sk;
    // occupancy clamp: 60 KiB -> exactly 2 blocks/CU (160/60 = 2.66 -> 2).
    // 512 blocks = 512 slots: uniform 2/CU placement, uniform full-tile work.
    char force[61440];
};

__global__ __launch_bounds__(512, 4)
void wasserstein_kernel(const float* __restrict__ x1, const float* __restrict__ x2,
                        const int* __restrict__ sz1, const int* __restrict__ sz2,
                        float* __restrict__ out)
{
    __shared__ SmemU  sm;
    __shared__ int    soff[16];
    __shared__ float  swred[8];

    const int b    = blockIdx.x;
    const int tid  = threadIdx.x;
    const int w    = tid >> 6;        // wave 0..7
    const int lane = tid & 63;
    const int rg   = lane >> 2;       // 0..15 : rows rg + 16*r   (r = 0..7)
    const int cg   = lane & 3;        // with w: cols (w*4+cg) + 32*c (c = 0..3)
    const int cb32 = (w << 2) | cg;   // 0..31

    // ---- exclusive prefix sums of sizes (512 threads: one element each) ----
    int a1 = (tid < b) ? sz1[tid] : 0;
    int a2 = (tid < b) ? sz2[tid] : 0;
#pragma unroll
    for (int d = 1; d < 64; d <<= 1) {
        a1 += __shfl_xor(a1, d);
        a2 += __shfl_xor(a2, d);
    }
    if (lane == 0) { soff[w] = a1; soff[8 + w] = a2; }
    if (tid < NMAXN) { sm.st.nA[tid] = 0.f; sm.st.nB[tid] = 0.f; }
    __syncthreads();
    int off1 = 0, off2 = 0;
#pragma unroll
    for (int i = 0; i < 8; ++i) { off1 += soff[i]; off2 += soff[8 + i]; }
    const int n1 = sz1[b];
    const int n2 = sz2[b];

    // ---- stage sets in D-chunks of 32, accumulate dots + norms ----
    float lk[8][4];   // starts as dot accumulator, becomes logK2
#pragma unroll
    for (int r = 0; r < 8; ++r)
#pragma unroll
        for (int c = 0; c < 4; ++c) lk[r][c] = 0.f;

    const int srow = tid >> 2;  // 0..127
    const int sq   = tid & 3;   // 8-float slice of the 32-col chunk

    for (int ch = 0; ch < 2; ++ch) {
        const float* p1 = x1 + (size_t)(off1 + srow) * DD + ch * 32 + sq * 8;
        const float* p2 = x2 + (size_t)(off2 + srow) * DD + ch * 32 + sq * 8;
        const bool ok1 = srow < n1;
        const bool ok2 = srow < n2;
        float va[8], vb[8];
#pragma unroll
        for (int qq = 0; qq < 2; ++qq) {
            float4 t1 = ok1 ? ((const float4*)p1)[qq] : make_float4(0.f, 0.f, 0.f, 0.f);
            float4 t2 = ok2 ? ((const float4*)p2)[qq] : make_float4(0.f, 0.f, 0.f, 0.f);
            va[4*qq+0] = t1.x; va[4*qq+1] = t1.y; va[4*qq+2] = t1.z; va[4*qq+3] = t1.w;
            vb[4*qq+0] = t2.x; vb[4*qq+1] = t2.y; vb[4*qq+2] = t2.z; vb[4*qq+3] = t2.w;
        }
        float s1 = 0.f, s2 = 0.f;
#pragma unroll
        for (int j = 0; j < 8; ++j) {
            sm.st.A[srow * 33 + sq * 8 + j] = va[j];
            sm.st.B[srow * 33 + sq * 8 + j] = vb[j];
            s1 += va[j] * va[j];
            s2 += vb[j] * vb[j];
        }
        s1 += __shfl_xor(s1, 1); s1 += __shfl_xor(s1, 2);
        s2 += __shfl_xor(s2, 1); s2 += __shfl_xor(s2, 2);
        if (sq == 0) { sm.st.nA[srow] += s1; sm.st.nB[srow] += s2; }
        __syncthreads();
#pragma unroll 2
        for (int d = 0; d < 32; ++d) {
            float av[8], bv[4];
#pragma unroll
            for (int r = 0; r < 8; ++r) av[r] = sm.st.A[(rg + 16*r) * 33 + d];
#pragma unroll
            for (int c = 0; c < 4; ++c) bv[c] = sm.st.B[(cb32 + 32*c) * 33 + d];
#pragma unroll
            for (int r = 0; r < 8; ++r)
#pragma unroll
                for (int c = 0; c < 4; ++c)
                    lk[r][c] = fmaf(av[r], bv[c], lk[r][c]);
        }
        __syncthreads();
    }

    // logK2 = -M*log2e/eps, M = ||a||^2 + ||b||^2 - 2ab (clamped >= 0)
    float lb[4];
    const float lbv = flog2((float)n1) - flog2((float)n2);
    {
        float rn1[8], rn2[4];
#pragma unroll
        for (int r = 0; r < 8; ++r) rn1[r] = sm.st.nA[rg + 16*r];
#pragma unroll
        for (int c = 0; c < 4; ++c) rn2[c] = sm.st.nB[cb32 + 32*c];
#pragma unroll
        for (int r = 0; r < 8; ++r)
#pragma unroll
            for (int c = 0; c < 4; ++c) {
                float M = rn1[r] + rn2[c] - 2.f * lk[r][c];
                lk[r][c] = fmaxf(M, 0.f) * LKSC;
            }
#pragma unroll
        for (int c = 0; c < 4; ++c)
            lb[c] = (cb32 + 32*c < n2) ? lbv : NEG2;
    }
    __syncthreads();   // retire staging view of the union

    // ---- Sinkhorn (log2 domain); v fully in-lane; u via coop combine ----
    const int   crow   = tid >> 2;                  // coop-combine row 0..127
    const int   q      = tid & 3;
    const float lacrow = (crow < n1) ? 0.f : NEG2;

    float uloc[8], v[4];
#pragma unroll
    for (int r = 0; r < 8; ++r) uloc[r] = 0.f;

    for (int k = 0; k < MAX_ITERS; ++k) {
        // ===== phase V (in-wave): v_c = lb_c - lse_r(lk[r][c] + u[r]) =====
        float mx[4], sc[4];
#pragma unroll
        for (int c = 0; c < 4; ++c) mx[c] = lk[0][c] + uloc[0];
#pragma unroll
        for (int r = 1; r < 8; ++r)
#pragma unroll
            for (int c = 0; c < 4; ++c)
                mx[c] = fmaxf(mx[c], lk[r][c] + uloc[r]);
#pragma unroll
        for (int c = 0; c < 4; ++c) {   // reduce over 16 row-groups
            mx[c] = fmaxf(mx[c], __shfl_xor(mx[c], 4));
            mx[c] = fmaxf(mx[c], __shfl_xor(mx[c], 8));
            mx[c] = fmaxf(mx[c], __shfl_xor(mx[c], 16));
            mx[c] = fmaxf(mx[c], __shfl_xor(mx[c], 32));
        }
#pragma unroll
        for (int c = 0; c < 4; ++c) sc[c] = fexp2(lk[0][c] + uloc[0] - mx[c]);
#pragma unroll
        for (int r = 1; r < 8; ++r)
#pragma unroll
            for (int c = 0; c < 4; ++c)
                sc[c] += fexp2(lk[r][c] + uloc[r] - mx[c]);
#pragma unroll
        for (int c = 0; c < 4; ++c) {
            sc[c] += __shfl_xor(sc[c], 4);
            sc[c] += __shfl_xor(sc[c], 8);
            sc[c] += __shfl_xor(sc[c], 16);
            sc[c] += __shfl_xor(sc[c], 32);
        }
#pragma unroll
        for (int c = 0; c < 4; ++c)
            v[c] = lb[c] - (mx[c] + flog2(sc[c]));

        // ===== phase U partials: per-wave (max,sum) over its 16-col slice ====
#pragma unroll
        for (int r = 0; r < 8; ++r) {
            float mr = lk[r][0] + v[0];
#pragma unroll
            for (int c = 1; c < 4; ++c) mr = fmaxf(mr, lk[r][c] + v[c]);
            mr = fmaxf(mr, __shfl_xor(mr, 1));
            mr = fmaxf(mr, __shfl_xor(mr, 2));
            float sr = fexp2(lk[r][0] + v[0] - mr);
#pragma unroll
            for (int c = 1; c < 4; ++c) sr += fexp2(lk[r][c] + v[c] - mr);
            sr += __shfl_xor(sr, 1);
            sr += __shfl_xor(sr, 2);
            if ((r & 3) == cg)   // one writer per (row, wave)
                sm.sk.part[(rg + 16*r) * 10 + w] = make_float2(mr, sr);
        }
        __syncthreads();                               // B1

        // ===== cooperative combine: 4 lanes per row fold 8 partials =========
        float4 t = *(const float4*)&sm.sk.part[crow * 10 + 2 * q];  // (m0,s0,m1,s1)
        float m = fmaxf(t.x, t.z);
        float s = t.y * fexp2(t.x - m) + t.w * fexp2(t.z - m);
        float mo = __shfl_xor(m, 1), so = __shfl_xor(s, 1);
        float mm = fmaxf(m, mo);
        s = s * fexp2(m - mm) + so * fexp2(mo - mm); m = mm;
        mo = __shfl_xor(m, 2); so = __shfl_xor(s, 2);
        mm = fmaxf(m, mo);
        s = s * fexp2(m - mm) + so * fexp2(mo - mm); m = mm;
        if (q == 0) sm.sk.u[crow] = lacrow - (m + flog2(s));
        __syncthreads();                               // B2

#pragma unroll
        for (int r = 0; r < 8; ++r) uloc[r] = sm.sk.u[rg + 16*r];
    }

    // ---- epilogue: out_b = OUTSC * sum_ij lk_ij * 2^(lk+u+v) ----
    float acc = 0.f;
#pragma unroll
    for (int r = 0; r < 8; ++r)
#pragma unroll
        for (int c = 0; c < 4; ++c)
            acc += lk[r][c] * fexp2(lk[r][c] + uloc[r] + v[c]);
#pragma unroll
    for (int d = 1; d < 64; d <<= 1) acc += __shfl_xor(acc, d);
    if (lane == 0) swred[w] = acc;
    __syncthreads();
    if (tid == 0) {
        float s = 0.f;
#pragma unroll
        for (int i = 0; i < 8; ++i) s += swred[i];
        out[b] = s * OUTSC;
    }
}

extern "C" void kernel_launch(void* const* d_in, const int* in_sizes, int n_in,
                              void* d_out, int out_size, void* d_ws, size_t ws_size,
                              hipStream_t stream) {
    const float* x1  = (const float*)d_in[0];
    const float* x2  = (const float*)d_in[1];
    const int*   sz1 = (const int*)d_in[2];
    const int*   sz2 = (const int*)d_in[3];
    float* out = (float*)d_out;
    hipLaunchKernelGGL(wasserstein_kernel, dim3(512), dim3(512), 0, stream,
                       x1, x2, sz1, sz2, out);
}